// Round 2
// baseline (139.924 us; speedup 1.0000x reference)
//
#include <hip/hip_runtime.h>

// WaveletLayer on [4096,4096] fp32:
//   out = diag_s * DWT3( diag_g * (DWT3(diag_b * x))[perm] )
// Haar DWT3 packet layout: [cA3(512) | cD3(512) | cD2(1024) | cD1(2048)].
//
// Key structure: thread t owns 16 CONTIGUOUS elements [16t, 16t+16) of its
// row, so all 3 Haar butterfly levels run entirely in registers. LDS is used
// exactly once (scatter packet layout -> barrier -> random permutation
// gather). 1 barrier per block total.

#define D   4096
#define NT  256            // 16 elements / thread

#define C_INV_SQRT2 0.70710678118654752440f

// XOR swizzle: breaks the power-of-2 stride patterns of the scatter writes
// (banks = addr%32) without affecting the (already random) gather.
static __device__ __forceinline__ int swz(int i) {
    return i ^ ((i >> 5) & 31);
}

// 3 in-register Haar levels on 16 contiguous elements.
// in : v[16]  (elements [16t,16t+16))
// out: a3[2] (cA3 @ 2t), d3[2] (cD3 @ 2t), d2[4] (cD2 @ 4t), d1[8] (cD1 @ 8t)
static __device__ __forceinline__ void dwt3_reg(const float v[16],
                                                float a3[2], float d3[2],
                                                float d2[4], float d1[8]) {
    float a1[8];
    #pragma unroll
    for (int j = 0; j < 8; ++j) {
        a1[j] = (v[2 * j] + v[2 * j + 1]) * C_INV_SQRT2;
        d1[j] = (v[2 * j] - v[2 * j + 1]) * C_INV_SQRT2;
    }
    float a2[4];
    #pragma unroll
    for (int j = 0; j < 4; ++j) {
        a2[j] = (a1[2 * j] + a1[2 * j + 1]) * C_INV_SQRT2;
        d2[j] = (a1[2 * j] - a1[2 * j + 1]) * C_INV_SQRT2;
    }
    #pragma unroll
    for (int j = 0; j < 2; ++j) {
        a3[j] = (a2[2 * j] + a2[2 * j + 1]) * C_INV_SQRT2;
        d3[j] = (a2[2 * j] - a2[2 * j + 1]) * C_INV_SQRT2;
    }
}

__global__ __launch_bounds__(NT) void wavelet_row_kernel(
    const float* __restrict__ x,
    const float* __restrict__ diag_s,
    const float* __restrict__ diag_g,
    const float* __restrict__ diag_b,
    const int*   __restrict__ perm,
    float*       __restrict__ out)
{
    __shared__ float buf[D];

    const int t = threadIdx.x;
    const size_t row = blockIdx.x;

    // ---- load 16 contiguous x * diag_b into registers ----
    float v[16];
    {
        const float4* x4 = (const float4*)(x + row * (size_t)D);
        const float4* b4 = (const float4*)diag_b;
        #pragma unroll
        for (int k = 0; k < 4; ++k) {
            float4 xv = x4[4 * t + k];
            float4 bv = b4[4 * t + k];
            v[4 * k + 0] = xv.x * bv.x;
            v[4 * k + 1] = xv.y * bv.y;
            v[4 * k + 2] = xv.z * bv.z;
            v[4 * k + 3] = xv.w * bv.w;
        }
    }

    // ---- DWT #1 fully in registers ----
    float a3[2], d3[2], d2[4], d1[8];
    dwt3_reg(v, a3, d3, d2, d1);

    // ---- scatter packet layout to LDS (swizzled addressing) ----
    #pragma unroll
    for (int j = 0; j < 2; ++j) buf[swz(2 * t + j)]        = a3[j];
    #pragma unroll
    for (int j = 0; j < 2; ++j) buf[swz(512 + 2 * t + j)]  = d3[j];
    #pragma unroll
    for (int j = 0; j < 4; ++j) buf[swz(1024 + 4 * t + j)] = d2[j];
    #pragma unroll
    for (int j = 0; j < 8; ++j) buf[swz(2048 + 8 * t + j)] = d1[j];

    __syncthreads();   // the only barrier

    // ---- permutation gather + diag_g into registers (contiguous per thread) ----
    float w[16];
    {
        const int4*   p4 = (const int4*)perm;
        const float4* g4 = (const float4*)diag_g;
        int pidx[16];
        #pragma unroll
        for (int k = 0; k < 4; ++k) {
            int4 pv = p4[4 * t + k];
            pidx[4 * k + 0] = pv.x;
            pidx[4 * k + 1] = pv.y;
            pidx[4 * k + 2] = pv.z;
            pidx[4 * k + 3] = pv.w;
        }
        #pragma unroll
        for (int k = 0; k < 4; ++k) {
            float4 gv = g4[4 * t + k];
            w[4 * k + 0] = buf[swz(pidx[4 * k + 0])] * gv.x;
            w[4 * k + 1] = buf[swz(pidx[4 * k + 1])] * gv.y;
            w[4 * k + 2] = buf[swz(pidx[4 * k + 2])] * gv.z;
            w[4 * k + 3] = buf[swz(pidx[4 * k + 3])] * gv.w;
        }
    }

    // ---- DWT #2 fully in registers ----
    float b3[2], e3[2], e2[4], e1[8];
    dwt3_reg(w, b3, e3, e2, e1);

    // ---- multiply diag_s and store (coalesced float2/float4) ----
    float* orow = out + row * (size_t)D;
    {
        // cA3: floats [2t, 2t+1]  -> float2 index t
        const float2* s2 = (const float2*)diag_s;
        float2* o2 = (float2*)orow;
        float2 sv, ov;
        sv = s2[t];
        ov.x = b3[0] * sv.x; ov.y = b3[1] * sv.y;
        o2[t] = ov;
        // cD3: floats [512+2t, 512+2t+1] -> float2 index 256+t
        sv = s2[256 + t];
        ov.x = e3[0] * sv.x; ov.y = e3[1] * sv.y;
        o2[256 + t] = ov;
    }
    {
        const float4* s4 = (const float4*)diag_s;
        float4* o4 = (float4*)orow;
        // cD2: floats [1024+4t ..) -> float4 index 256+t
        float4 sv = s4[256 + t];
        float4 ov;
        ov.x = e2[0] * sv.x; ov.y = e2[1] * sv.y;
        ov.z = e2[2] * sv.z; ov.w = e2[3] * sv.w;
        o4[256 + t] = ov;
        // cD1: floats [2048+8t ..) -> float4 indices 512+2t, 512+2t+1
        #pragma unroll
        for (int k = 0; k < 2; ++k) {
            float4 sw = s4[512 + 2 * t + k];
            float4 ow;
            ow.x = e1[4 * k + 0] * sw.x; ow.y = e1[4 * k + 1] * sw.y;
            ow.z = e1[4 * k + 2] * sw.z; ow.w = e1[4 * k + 3] * sw.w;
            o4[512 + 2 * t + k] = ow;
        }
    }
}

extern "C" void kernel_launch(void* const* d_in, const int* in_sizes, int n_in,
                              void* d_out, int out_size, void* d_ws, size_t ws_size,
                              hipStream_t stream) {
    // setup_inputs() order: x, diag_s, diag_g, diag_b, dec_lo, dec_hi, perm, scales
    const float* x      = (const float*)d_in[0];
    const float* diag_s = (const float*)d_in[1];
    const float* diag_g = (const float*)d_in[2];
    const float* diag_b = (const float*)d_in[3];
    const int* perm     = (const int*)d_in[6];
    float* out          = (float*)d_out;

    const int B = 4096;
    wavelet_row_kernel<<<B, NT, 0, stream>>>(x, diag_s, diag_g, diag_b, perm, out);
}

// Round 4
// 129.253 us; speedup vs baseline: 1.0826x; 1.0826x over previous
//
#include <hip/hip_runtime.h>

// WaveletLayer on [4096,4096] fp32:
//   out = diag_s * DWT3( diag_g * (DWT3(diag_b * x))[perm] )
// Haar DWT3 packet layout: [cA3(512) | cD3(512) | cD2(1024) | cD1(2048)].
//
// Block of 256 threads processes R=4 rows. Row-invariant tables (diag_b,
// diag_g, diag_s, perm) are loaded into registers ONCE per block and reused
// across rows — cuts table traffic (was 80 KB/block/row vs 16 KB row data)
// by 4x. DWTs run fully in registers (thread owns 16 contiguous columns);
// LDS only for the permutation round-trip, double-buffered, 1 barrier/row.

#define D   4096
#define NT  256            // 16 columns / thread
#define R   4              // rows per block

#define C_INV_SQRT2 0.70710678118654752440f

// native clang vector types (accepted by __builtin_nontemporal_store)
typedef float vf2 __attribute__((ext_vector_type(2)));
typedef float vf4 __attribute__((ext_vector_type(4)));

// XOR swizzle to break power-of-2 patterns on the scatter writes.
static __device__ __forceinline__ int swz(int i) {
    return i ^ ((i >> 5) & 31);
}

// 3 in-register Haar levels on 16 contiguous elements.
static __device__ __forceinline__ void dwt3_reg(const float v[16],
                                                float a3[2], float d3[2],
                                                float d2[4], float d1[8]) {
    float a1[8];
    #pragma unroll
    for (int j = 0; j < 8; ++j) {
        a1[j] = (v[2 * j] + v[2 * j + 1]) * C_INV_SQRT2;
        d1[j] = (v[2 * j] - v[2 * j + 1]) * C_INV_SQRT2;
    }
    float a2[4];
    #pragma unroll
    for (int j = 0; j < 4; ++j) {
        a2[j] = (a1[2 * j] + a1[2 * j + 1]) * C_INV_SQRT2;
        d2[j] = (a1[2 * j] - a1[2 * j + 1]) * C_INV_SQRT2;
    }
    #pragma unroll
    for (int j = 0; j < 2; ++j) {
        a3[j] = (a2[2 * j] + a2[2 * j + 1]) * C_INV_SQRT2;
        d3[j] = (a2[2 * j] - a2[2 * j + 1]) * C_INV_SQRT2;
    }
}

__global__ __launch_bounds__(NT) void wavelet_rows_kernel(
    const float* __restrict__ x,
    const float* __restrict__ diag_s,
    const float* __restrict__ diag_g,
    const float* __restrict__ diag_b,
    const int*   __restrict__ perm,
    float*       __restrict__ out)
{
    __shared__ float buf[2][D];

    const int t = threadIdx.x;
    const size_t row0 = (size_t)blockIdx.x * R;

    // ---- load row-invariant tables into registers (once per block) ----
    float db[16], dg[16];
    int   pidx[16];
    {
        const vf4* b4 = (const vf4*)diag_b;
        const vf4* g4 = (const vf4*)diag_g;
        const int4* p4 = (const int4*)perm;
        #pragma unroll
        for (int k = 0; k < 4; ++k) {
            vf4 bv = b4[4 * t + k];
            db[4 * k + 0] = bv.x; db[4 * k + 1] = bv.y;
            db[4 * k + 2] = bv.z; db[4 * k + 3] = bv.w;
            vf4 gv = g4[4 * t + k];
            dg[4 * k + 0] = gv.x; dg[4 * k + 1] = gv.y;
            dg[4 * k + 2] = gv.z; dg[4 * k + 3] = gv.w;
            int4 pv = p4[4 * t + k];
            pidx[4 * k + 0] = pv.x; pidx[4 * k + 1] = pv.y;
            pidx[4 * k + 2] = pv.z; pidx[4 * k + 3] = pv.w;
        }
    }
    // diag_s at the thread-fixed packet store positions:
    vf2 sA, sD3;
    vf4 sD2, sD1a, sD1b;
    {
        const vf2* s2 = (const vf2*)diag_s;
        const vf4* s4 = (const vf4*)diag_s;
        sA   = s2[t];               // floats 2t, 2t+1      (cA3)
        sD3  = s2[256 + t];         // floats 512+2t..      (cD3)
        sD2  = s4[256 + t];         // floats 1024+4t..     (cD2)
        sD1a = s4[512 + 2 * t];     // floats 2048+8t..     (cD1)
        sD1b = s4[512 + 2 * t + 1];
    }

    // ---- row loop ----
    for (int r = 0; r < R; ++r) {
        float* b = buf[r & 1];
        const vf4* x4 = (const vf4*)(x + (row0 + r) * (size_t)D);

        // load 16 contiguous x, multiply diag_b
        float v[16];
        #pragma unroll
        for (int k = 0; k < 4; ++k) {
            vf4 xv = x4[4 * t + k];
            v[4 * k + 0] = xv.x * db[4 * k + 0];
            v[4 * k + 1] = xv.y * db[4 * k + 1];
            v[4 * k + 2] = xv.z * db[4 * k + 2];
            v[4 * k + 3] = xv.w * db[4 * k + 3];
        }

        // DWT #1 in registers
        float a3[2], d3[2], d2[4], d1[8];
        dwt3_reg(v, a3, d3, d2, d1);

        // scatter packet layout to LDS (swizzled)
        #pragma unroll
        for (int j = 0; j < 2; ++j) b[swz(2 * t + j)]        = a3[j];
        #pragma unroll
        for (int j = 0; j < 2; ++j) b[swz(512 + 2 * t + j)]  = d3[j];
        #pragma unroll
        for (int j = 0; j < 4; ++j) b[swz(1024 + 4 * t + j)] = d2[j];
        #pragma unroll
        for (int j = 0; j < 8; ++j) b[swz(2048 + 8 * t + j)] = d1[j];

        __syncthreads();

        // permutation gather * diag_g
        float w[16];
        #pragma unroll
        for (int k = 0; k < 16; ++k) {
            w[k] = b[swz(pidx[k])] * dg[k];
        }

        // DWT #2 in registers
        float b3[2], e3[2], e2[4], e1[8];
        dwt3_reg(w, b3, e3, e2, e1);

        // multiply diag_s, nontemporal coalesced store
        float* orow = out + (row0 + r) * (size_t)D;
        {
            vf2* o2 = (vf2*)orow;
            vf2 ov;
            ov.x = b3[0] * sA.x;  ov.y = b3[1] * sA.y;
            __builtin_nontemporal_store(ov, &o2[t]);
            ov.x = e3[0] * sD3.x; ov.y = e3[1] * sD3.y;
            __builtin_nontemporal_store(ov, &o2[256 + t]);

            vf4* o4 = (vf4*)orow;
            vf4 o;
            o.x = e2[0] * sD2.x; o.y = e2[1] * sD2.y;
            o.z = e2[2] * sD2.z; o.w = e2[3] * sD2.w;
            __builtin_nontemporal_store(o, &o4[256 + t]);
            o.x = e1[0] * sD1a.x; o.y = e1[1] * sD1a.y;
            o.z = e1[2] * sD1a.z; o.w = e1[3] * sD1a.w;
            __builtin_nontemporal_store(o, &o4[512 + 2 * t]);
            o.x = e1[4] * sD1b.x; o.y = e1[5] * sD1b.y;
            o.z = e1[6] * sD1b.z; o.w = e1[7] * sD1b.w;
            __builtin_nontemporal_store(o, &o4[512 + 2 * t + 1]);
        }
        // No extra barrier needed: scatter into buf[(r+2)&1] happens after
        // the barrier of row r+1, which follows this row's gather in
        // program order on every wave.
    }
}

extern "C" void kernel_launch(void* const* d_in, const int* in_sizes, int n_in,
                              void* d_out, int out_size, void* d_ws, size_t ws_size,
                              hipStream_t stream) {
    // setup_inputs() order: x, diag_s, diag_g, diag_b, dec_lo, dec_hi, perm, scales
    const float* x      = (const float*)d_in[0];
    const float* diag_s = (const float*)d_in[1];
    const float* diag_g = (const float*)d_in[2];
    const float* diag_b = (const float*)d_in[3];
    const int* perm     = (const int*)d_in[6];
    float* out          = (float*)d_out;

    const int B = 4096 / R;
    wavelet_rows_kernel<<<B, NT, 0, stream>>>(x, diag_s, diag_g, diag_b, perm, out);
}